// Round 10
// baseline (326.366 us; speedup 1.0000x reference)
//
#include <hip/hip_runtime.h>
#include <hip/hip_fp16.h>
#include <cstdint>
#include <cstddef>

// ---------------------------------------------------------------------------
// LightGCN on MI355X — atomic-free CSR build + fp16 Y-scaled gather storage.
//   Y-substitution: Y_l = diag(deg^-1/2) X_l => Y_{l+1} = (1/deg)*sum Y_l[c]
//     -> SpMM inner loop is a pure gather-sum (pk_add pre-add + mad_mix).
//   Reduction: halving butterfly (select/shfl/add, 7 ops/rnd-total) — each
//     lane ends owning ONE dim element; epilogue = 1 cvt + 1 2B store.
//   CSR build: bucket partition -> bucket_scan -> finalize (rank+cv, and
//     FUSED Y0 convert for the bucket's 256 rows).
//   Layer 3 fused into batch gather (X_l = Y_l*invd; X0 from fp32 tables).
// ---------------------------------------------------------------------------

typedef __attribute__((ext_vector_type(8))) _Float16 half8;

#define NB_SHIFT 8
#define BCAP 16000      // max edges per 256-row bucket (expected max ~10.7K)
#define P1_TILE 8192
#define P1_DIM 512

// ---- partition into fixed-capacity bucket regions (bcur = per-bucket delta) ----
__global__ __launch_bounds__(P1_DIM) void partition_kernel(
    const int* __restrict__ rows, const int* __restrict__ cols,
    int* __restrict__ bucket_cursor, int* __restrict__ tmp,
    int nnz, int nb) {
    __shared__ int            lhist[1024];
    __shared__ int            loff[1024];
    __shared__ int            ldelta[1024];   // dest_base[b] - loff[b]
    __shared__ int            wsum[8];
    __shared__ int            stage[P1_TILE]; // packed (r_local<<18)|col
    __shared__ unsigned short bstage[P1_TILE];
    int t = threadIdx.x;
    int lane = t & 63, wv = t >> 6;
    int base     = blockIdx.x * P1_TILE;
    int cnt_here = min(P1_TILE, nnz - base);
    int full4    = cnt_here >> 2;
    int rem      = cnt_here & 3;
    for (int i = t; i < 1024; i += P1_DIM) lhist[i] = 0;
    __syncthreads();
    const int4* rows4 = (const int4*)(rows + base);
    const int4* cols4 = (const int4*)(cols + base);
    int4 rr[4], cc[4];
    int  rk[16];
#pragma unroll
    for (int k = 0; k < 4; ++k) {
        int i4 = t + k * P1_DIM;
        if (i4 < full4) {
            rr[k] = rows4[i4];
            cc[k] = cols4[i4];
            rk[4 * k + 0] = atomicAdd(&lhist[rr[k].x >> NB_SHIFT], 1);
            rk[4 * k + 1] = atomicAdd(&lhist[rr[k].y >> NB_SHIFT], 1);
            rk[4 * k + 2] = atomicAdd(&lhist[rr[k].z >> NB_SHIFT], 1);
            rk[4 * k + 3] = atomicAdd(&lhist[rr[k].w >> NB_SHIFT], 1);
        }
    }
    int re = 0, ce = 0, rke = 0;
    bool has_rem = (t < rem);
    if (has_rem) {
        re  = rows[base + 4 * full4 + t];
        ce  = cols[base + 4 * full4 + t];
        rke = atomicAdd(&lhist[re >> NB_SHIFT], 1);
    }
    __syncthreads();
    // wave-shuffle exclusive scan over 1024 bucket counts (2 per thread)
    int v0 = lhist[2 * t], v1 = lhist[2 * t + 1];
    int ts = v0 + v1;
    int sc = ts;
#pragma unroll
    for (int off = 1; off < 64; off <<= 1) {
        int x = __shfl_up(sc, off);
        if (lane >= off) sc += x;
    }
    if (lane == 63) wsum[wv] = sc;
    __syncthreads();
    int prefix = 0;
#pragma unroll
    for (int k = 0; k < 8; ++k) {
        int s = wsum[k];
        prefix += (k < wv) ? s : 0;
    }
    int run = prefix + sc - ts;  // exclusive prefix of ts
    loff[2 * t]     = run;
    loff[2 * t + 1] = run + v0;
#pragma unroll
    for (int k = 0; k < 2; ++k) {
        int b  = 2 * t + k;
        int vv = (k == 0) ? v0 : v1;
        if (b < nb && vv > 0) {
            int old = atomicAdd(&bucket_cursor[b], vv);   // delta in bucket
            ldelta[b] = b * BCAP + old - loff[b];
        }
    }
    __syncthreads();
#pragma unroll
    for (int k = 0; k < 4; ++k) {
        int i4 = t + k * P1_DIM;
        if (i4 < full4) {
            int r4[4] = {rr[k].x, rr[k].y, rr[k].z, rr[k].w};
            int c4[4] = {cc[k].x, cc[k].y, cc[k].z, cc[k].w};
#pragma unroll
            for (int e = 0; e < 4; ++e) {
                int b = r4[e] >> NB_SHIFT;
                int s = loff[b] + rk[4 * k + e];
                stage[s]  = ((r4[e] & 255) << 18) | c4[e];
                bstage[s] = (unsigned short)b;
            }
        }
    }
    if (has_rem) {
        int b = re >> NB_SHIFT;
        int s = loff[b] + rke;
        stage[s]  = ((re & 255) << 18) | ce;
        bstage[s] = (unsigned short)b;
    }
    __syncthreads();
    for (int s = t; s < cnt_here; s += P1_DIM) {
        tmp[s + ldelta[bstage[s]]] = stage[s];
    }
}

// ---- exclusive scan of per-bucket counts ----
__global__ __launch_bounds__(256) void bucket_scan_kernel(
    const int* __restrict__ bcur, int* __restrict__ bucket_base,
    int nb, int nnz) {
    __shared__ int sdata[256];
    int t = threadIdx.x;
    int v[3];
#pragma unroll
    for (int k = 0; k < 3; ++k) {
        int i = 3 * t + k;
        v[k] = (i < nb) ? bcur[i] : 0;
    }
    int ts = v[0] + v[1] + v[2];
    sdata[t] = ts;
    __syncthreads();
    for (int off = 1; off < 256; off <<= 1) {
        int x = 0;
        if (t >= off) x = sdata[t - off];
        __syncthreads();
        if (t >= off) sdata[t] += x;
        __syncthreads();
    }
    int run = sdata[t] - ts;
#pragma unroll
    for (int k = 0; k < 3; ++k) {
        int i = 3 * t + k;
        if (i < nb) {
            bucket_base[i] = run;
            run += v[k];
        }
    }
    if (t == 255) bucket_base[nb] = nnz;
}

// ---- per-bucket finalize: row_ptr, dis/dis2/invd, cv, FUSED Y0 convert ----
__global__ __launch_bounds__(256) void finalize_kernel(
    const int* __restrict__ tmp, const int* __restrict__ bucket_base,
    const float4* __restrict__ ut4, const float4* __restrict__ it4,
    int* __restrict__ row_ptr, float* __restrict__ dis,
    float* __restrict__ dis2, float* __restrict__ invd,
    int* __restrict__ cv, half8* __restrict__ Yh0,
    int usernum, int n_nodes, int nb, int nnz) {
    __shared__ int   rcnt[256];
    __shared__ int   ccur[256];
    __shared__ int   wsum[4];
    __shared__ float sdis[256];
    int b = blockIdx.x;
    int t = threadIdx.x;
    int lane = t & 63, wv = t >> 6;
    int src   = b * BCAP;
    int dbeg  = bucket_base[b];
    int count = bucket_base[b + 1] - dbeg;
    rcnt[t] = 0;
    __syncthreads();
    for (int i = t; i < count; i += 256) {
        atomicAdd(&rcnt[tmp[src + i] >> 18], 1);
    }
    __syncthreads();
    int v = rcnt[t];
    int sc = v;
#pragma unroll
    for (int off = 1; off < 64; off <<= 1) {
        int x = __shfl_up(sc, off);
        if (lane >= off) sc += x;
    }
    if (lane == 63) wsum[wv] = sc;
    __syncthreads();
    int prefix = 0;
#pragma unroll
    for (int k = 0; k < 4; ++k) {
        int s = wsum[k];
        prefix += (k < wv) ? s : 0;
    }
    int ex = prefix + sc - v;
    ccur[t] = ex;
    int row = (b << NB_SHIFT) + t;
    float dval = 0.0f;
    if (row < n_nodes) {
        row_ptr[row] = dbeg + ex;
        double dv = (double)v;
        dval      = (v > 0) ? (float)(1.0 / sqrt(dv)) : 0.0f;
        dis[row]  = dval;
        dis2[row] = (v > 0) ? (float)(1.0 / dv) : 0.0f;
        invd[row] = (v > 0) ? (float)sqrt(dv) : 0.0f;
    }
    sdis[t] = dval;
    if (b == nb - 1 && t == 0) row_ptr[n_nodes] = nnz;
    __syncthreads();
    // rank + direct cv write: dest window ~28KB -> L2 write-merge
    for (int i = t; i < count; i += 256) {
        int p  = tmp[src + i];
        int rk = atomicAdd(&ccur[p >> 18], 1);
        cv[dbeg + rk] = p & 0x3FFFF;
    }
    // fused convert: Y0[row] = dis[row] * X0[row] (fp16, 128B rows)
    int row0 = b << NB_SHIFT;
    for (int i = t; i < 256 * 8; i += 256) {
        int rl = i >> 3;
        int rg = row0 + rl;
        if (rg < n_nodes) {
            int c = i & 7;
            float d = sdis[rl];
            const float4* srcp = (rg <= usernum)
                ? (ut4 + (size_t)rg * 16 + 2 * c)
                : (it4 + (size_t)(rg - usernum) * 16 + 2 * c);
            float4 a = srcp[0];
            float4 e = srcp[1];
            half8 o;
            o[0] = (_Float16)(d * a.x); o[1] = (_Float16)(d * a.y);
            o[2] = (_Float16)(d * a.z); o[3] = (_Float16)(d * a.w);
            o[4] = (_Float16)(d * e.x); o[5] = (_Float16)(d * e.y);
            o[6] = (_Float16)(d * e.z); o[7] = (_Float16)(d * e.w);
            Yh0[(size_t)rg * 8 + c] = o;
        }
    }
}

// ---- pure gather-sum CSR row: 8 edge-slots x 8 lanes x half8 ----
// Halving-butterfly reduction: returns ONE element per lane, for
// dim d = l8*8 + k with k = (g&1)*4 + (g&2) + (g>>2).
__device__ inline float csr_row_sum_h(const _Float16* __restrict__ Yh,
                                      const int* __restrict__ cv,
                                      int beg, int end, int g, int l8,
                                      float one) {
    float acc[8] = {0.f, 0.f, 0.f, 0.f, 0.f, 0.f, 0.f, 0.f};
    const char* Yb = (const char*)Yh;
    const char* cb = (const char*)cv;
    unsigned lo = (unsigned)l8 * 16u;
    int j = beg + g;
    for (; j + 8 < end; j += 16) {
        unsigned c0 = (unsigned)*(const int*)(cb + ((unsigned)j << 2));
        unsigned c1 = (unsigned)*(const int*)(cb + ((unsigned)(j + 8) << 2));
        half8 x0 = *(const half8*)(Yb + (c0 << 7) + lo);
        half8 x1 = *(const half8*)(Yb + (c1 << 7) + lo);
        half8 tt = x0 + x1;   // 4x v_pk_add_f16
#pragma unroll
        for (int k = 0; k < 8; ++k) {
            acc[k] += one * (float)tt[k];   // v_mad_mix_f32
        }
    }
    if (j < end) {
        unsigned c0 = (unsigned)*(const int*)(cb + ((unsigned)j << 2));
        half8 x0 = *(const half8*)(Yb + (c0 << 7) + lo);
#pragma unroll
        for (int k = 0; k < 8; ++k) {
            acc[k] += one * (float)x0[k];
        }
    }
    bool gb0 = (g & 1) != 0;
    bool gb1 = (g & 2) != 0;
    bool gb2 = (g & 4) != 0;
    // round 1 (xor 8): keep 4 accs — lane keeps k-quad selected by gb0
    float s0 = gb0 ? acc[0] : acc[4];
    float s1 = gb0 ? acc[1] : acc[5];
    float s2 = gb0 ? acc[2] : acc[6];
    float s3 = gb0 ? acc[3] : acc[7];
    float a0 = (gb0 ? acc[4] : acc[0]) + __shfl_xor(s0, 8);
    float a1 = (gb0 ? acc[5] : acc[1]) + __shfl_xor(s1, 8);
    float a2 = (gb0 ? acc[6] : acc[2]) + __shfl_xor(s2, 8);
    float a3 = (gb0 ? acc[7] : acc[3]) + __shfl_xor(s3, 8);
    // round 2 (xor 16): keep 2
    float t0 = gb1 ? a0 : a2;
    float t1 = gb1 ? a1 : a3;
    float b0 = (gb1 ? a2 : a0) + __shfl_xor(t0, 16);
    float b1 = (gb1 ? a3 : a1) + __shfl_xor(t1, 16);
    // round 3 (xor 32): keep 1
    float u = gb2 ? b0 : b1;
    float fin = (gb2 ? b1 : b0) + __shfl_xor(u, 32);
    return fin;
}

__device__ inline int lane_dim(int g, int l8) {
    return l8 * 8 + ((g & 1) * 4 + (g & 2) + (g >> 2));
}

// Y_{l+1}[r] = (1/deg[r]) * sum_e Y_l[c]
__global__ __launch_bounds__(256) void spmm_y_kernel(
    const _Float16* __restrict__ Yin, _Float16* __restrict__ Yout,
    const int* __restrict__ row_ptr, const int* __restrict__ cv,
    const float* __restrict__ dis2, float one, int n_nodes) {
    int wid  = (blockIdx.x * blockDim.x + threadIdx.x) >> 6;
    int lane = threadIdx.x & 63;
    if (wid >= n_nodes) return;
    int beg = row_ptr[wid];
    int end = row_ptr[wid + 1];
    float d2 = dis2[wid];
    int g = lane >> 3, l8 = lane & 7;
    float fin = csr_row_sum_h(Yin, cv, beg, end, g, l8, one);
    int d = lane_dim(g, l8);
    Yout[(size_t)wid * 64 + d] = (_Float16)(fin * d2);
}

// fused layer-3 + gather:
// accb[w][d] = X0fp32[idx][d] + invd*(Y1[idx][d]+Y2[idx][d]) + dis*rowdot[d]
__global__ __launch_bounds__(256) void final_gather_kernel(
    const float* __restrict__ ut, const float* __restrict__ itb,
    const _Float16* __restrict__ Y1, const _Float16* __restrict__ Y2,
    const int* __restrict__ row_ptr, const int* __restrict__ cv,
    const float* __restrict__ dis, const float* __restrict__ invd,
    const int* __restrict__ user_ids, const int* __restrict__ pos_seqs,
    const int* __restrict__ neg_seqs, float* __restrict__ accb,
    float one, int usernum, int itemnum, int batch) {
    int w    = (blockIdx.x * blockDim.x + threadIdx.x) >> 6;
    int lane = threadIdx.x & 63;
    if (w >= 3 * batch) return;
    int which = w / batch;
    int b     = w - which * batch;
    int idx;
    const float* base0;
    if (which == 0) {
        int u = min(max(user_ids[b], 0), usernum);
        idx = u;
        base0 = ut + (size_t)u * 64;
    } else {
        const int* seq = (which == 1) ? pos_seqs : neg_seqs;
        int p = min(max(seq[b], 1), itemnum);
        idx = usernum + p;
        base0 = itb + (size_t)p * 64;
    }
    int beg = row_ptr[idx];
    int end = row_ptr[idx + 1];
    float dr = dis[idx];
    float iv = invd[idx];
    int g = lane >> 3, l8 = lane & 7;
    float fin = csr_row_sum_h(Y2, cv, beg, end, g, l8, one);
    int d = lane_dim(g, l8);
    float x0v = base0[d];
    float y1v = (float)Y1[(size_t)idx * 64 + d];
    float y2v = (float)Y2[(size_t)idx * 64 + d];
    accb[(size_t)w * 64 + d] = x0v + iv * (y1v + y2v) + fin * dr;
}

__global__ void logits_kernel(const float* __restrict__ acc,
                              float* __restrict__ out, int batch) {
    int w    = (blockIdx.x * blockDim.x + threadIdx.x) >> 6;
    int lane = threadIdx.x & 63;
    if (w >= batch) return;
    float u = acc[(size_t)w * 64 + lane];
    float p = acc[(size_t)(batch + w) * 64 + lane];
    float n = acc[(size_t)(2 * batch + w) * 64 + lane];
    float dp = u * p;
    float dn = u * n;
#pragma unroll
    for (int off = 32; off > 0; off >>= 1) {
        dp += __shfl_xor(dp, off, 64);
        dn += __shfl_xor(dn, off, 64);
    }
    if (lane == 0) {
        out[w]         = dp * 0.0625f;
        out[batch + w] = dn * 0.0625f;
    }
}

extern "C" void kernel_launch(void* const* d_in, const int* in_sizes, int n_in,
                              void* d_out, int out_size, void* d_ws,
                              size_t ws_size, hipStream_t stream) {
    const float* user_table = (const float*)d_in[0];
    const float* item_table = (const float*)d_in[1];
    const int*   rows       = (const int*)d_in[3];
    const int*   cols       = (const int*)d_in[4];
    const int*   user_ids   = (const int*)d_in[5];
    const int*   pos_seqs   = (const int*)d_in[6];
    const int*   neg_seqs   = (const int*)d_in[7];
    float*       out        = (float*)d_out;

    const int D = 64;
    int usernum = in_sizes[0] / D - 1;   // 100000
    int itemnum = in_sizes[1] / D - 1;   // 50000
    int nnz     = in_sizes[2];           // 4,000,000
    int batch   = in_sizes[5];           // 4096
    int n_nodes = usernum + itemnum + 1; // 150001
    int nb      = (n_nodes + (1 << NB_SHIFT) - 1) >> NB_SHIFT;  // 586

    // ---- workspace layout ----
    char* w = (char*)d_ws;
    auto alloc = [&](size_t bytes) {
        char* p = w;
        w += (bytes + 255) & ~(size_t)255;
        return p;
    };
    _Float16* Yh0   = (_Float16*)alloc((size_t)n_nodes * D * 2);  // 19.2 MB
    _Float16* Yh1   = (_Float16*)alloc((size_t)n_nodes * D * 2);  // 19.2 MB
    _Float16* Yh2   = (_Float16*)alloc((size_t)n_nodes * D * 2);  // 19.2 MB
    int*   cv       = (int*)alloc((size_t)nnz * 4);               // 16 MB
    int*   row_ptr  = (int*)alloc((size_t)(n_nodes + 1) * 4);
    float* dis      = (float*)alloc((size_t)n_nodes * 4);
    float* dis2     = (float*)alloc((size_t)n_nodes * 4);
    float* invd     = (float*)alloc((size_t)n_nodes * 4);
    int*   bbase    = (int*)alloc(4096);
    int*   bcur     = (int*)alloc(4096);
    float* accb     = (float*)alloc((size_t)3 * batch * D * 4);   // 3 MB
    // partition scratch: 586*16000*4 = 37.5 MB, aliases Yh1+Yh2 (38.4 MB);
    // dead after finalize; Yh1/Yh2 written only afterwards.
    int*   tmp      = (int*)Yh1;

    // ---- CSR build ----
    hipMemsetAsync(bcur, 0, 4096, stream);
    int p1_tiles = (nnz + P1_TILE - 1) / P1_TILE;
    partition_kernel<<<p1_tiles, P1_DIM, 0, stream>>>(rows, cols, bcur, tmp,
                                                      nnz, nb);
    bucket_scan_kernel<<<1, 256, 0, stream>>>(bcur, bbase, nb, nnz);
    finalize_kernel<<<nb, 256, 0, stream>>>(
        tmp, bbase, (const float4*)user_table, (const float4*)item_table,
        row_ptr, dis, dis2, invd, cv, (half8*)Yh0, usernum, n_nodes, nb, nnz);

    // ---- layers: Yh0 -> Yh1 -> Yh2 (pure gather-sum + 1/deg scale) ----
    const float one = 1.0f;
    int spmm_grid = (n_nodes + 3) / 4;
    spmm_y_kernel<<<spmm_grid, 256, 0, stream>>>(Yh0, Yh1, row_ptr, cv, dis2,
                                                 one, n_nodes);
    spmm_y_kernel<<<spmm_grid, 256, 0, stream>>>(Yh1, Yh2, row_ptr, cv, dis2,
                                                 one, n_nodes);

    // ---- fused layer-3 + gather ----
    int gather_grid = (3 * batch + 3) / 4;
    final_gather_kernel<<<gather_grid, 256, 0, stream>>>(
        user_table, item_table, Yh1, Yh2, row_ptr, cv, dis, invd, user_ids,
        pos_seqs, neg_seqs, accb, one, usernum, itemnum, batch);

    // ---- final logits ----
    logits_kernel<<<(batch + 3) / 4, 256, 0, stream>>>(accb, out, batch);
}

// Round 11
// 325.057 us; speedup vs baseline: 1.0040x; 1.0040x over previous
//
#include <hip/hip_runtime.h>
#include <hip/hip_fp16.h>
#include <cstdint>
#include <cstddef>

// ---------------------------------------------------------------------------
// LightGCN on MI355X — atomic-free CSR build + fp16 Y-scaled gather storage.
//   Mirror COO: rows=[u, U+it], cols=[U+it, u] — partition reads only the
//     first 2M source pairs and emits both directed edges.
//   Y-substitution: Y_l = diag(deg^-1/2) X_l => Y_{l+1} = (1/deg)*sum Y_l[c]
//     -> SpMM inner loop is a pure gather-sum (pk_add pre-add + mad_mix).
//   Reduction: halving butterfly — each lane ends owning ONE dim element.
//   finalize: self-computed bucket prefix (no bucket_scan kernel), per-row
//     hist/rank -> row_ptr, dis/dis2/invd, cv, fused Y0 convert.
//   gather_logits: one wave per batch element, 3 row-dots + wave dot.
//   6 dispatches total.
// ---------------------------------------------------------------------------

typedef __attribute__((ext_vector_type(8))) _Float16 half8;

#define NB_SHIFT 8
#define BCAP 16000      // max edges per 256-row bucket (expected max ~10.7K)
#define P1_SRC 4096     // source pairs per tile -> 8192 directed edges
#define P1_DIM 512

// ---- partition mirror pairs into fixed-capacity bucket regions ----
__global__ __launch_bounds__(P1_DIM) void partition_kernel(
    const int* __restrict__ rows, const int* __restrict__ cols,
    int* __restrict__ bucket_cursor, int* __restrict__ tmp,
    int M /* = nnz/2 */, int nb) {
    __shared__ int            lhist[1024];
    __shared__ int            loff[1024];
    __shared__ int            ldelta[1024];   // dest_base[b] - loff[b]
    __shared__ int            wsum[8];
    __shared__ int            stage[2 * P1_SRC];   // 32 KB
    __shared__ unsigned short bstage[2 * P1_SRC];  // 16 KB
    int t = threadIdx.x;
    int lane = t & 63, wv = t >> 6;
    int base     = blockIdx.x * P1_SRC;
    int cnt_here = min(P1_SRC, M - base);
    int full4    = cnt_here >> 2;
    int rem      = cnt_here & 3;
    for (int i = t; i < 1024; i += P1_DIM) lhist[i] = 0;
    __syncthreads();
    const int4* rows4 = (const int4*)(rows + base);
    const int4* cols4 = (const int4*)(cols + base);
    int4 uu[2], vv[2];
    int  rka[8], rkb[8];
#pragma unroll
    for (int k = 0; k < 2; ++k) {
        int i4 = t + k * P1_DIM;
        if (i4 < full4) {
            uu[k] = rows4[i4];
            vv[k] = cols4[i4];
            int u4[4] = {uu[k].x, uu[k].y, uu[k].z, uu[k].w};
            int v4[4] = {vv[k].x, vv[k].y, vv[k].z, vv[k].w};
#pragma unroll
            for (int e = 0; e < 4; ++e) {
                rka[4 * k + e] = atomicAdd(&lhist[u4[e] >> NB_SHIFT], 1);
                rkb[4 * k + e] = atomicAdd(&lhist[v4[e] >> NB_SHIFT], 1);
            }
        }
    }
    int ur = 0, vr = 0, rkra = 0, rkrb = 0;
    bool has_rem = (t < rem);
    if (has_rem) {
        ur = rows[base + 4 * full4 + t];
        vr = cols[base + 4 * full4 + t];
        rkra = atomicAdd(&lhist[ur >> NB_SHIFT], 1);
        rkrb = atomicAdd(&lhist[vr >> NB_SHIFT], 1);
    }
    __syncthreads();
    // wave-shuffle exclusive scan over 1024 bucket counts (2 per thread)
    int v0 = lhist[2 * t], v1 = lhist[2 * t + 1];
    int ts = v0 + v1;
    int sc = ts;
#pragma unroll
    for (int off = 1; off < 64; off <<= 1) {
        int x = __shfl_up(sc, off);
        if (lane >= off) sc += x;
    }
    if (lane == 63) wsum[wv] = sc;
    __syncthreads();
    int prefix = 0;
#pragma unroll
    for (int k = 0; k < 8; ++k) {
        int s = wsum[k];
        prefix += (k < wv) ? s : 0;
    }
    int run = prefix + sc - ts;  // exclusive prefix of ts
    loff[2 * t]     = run;
    loff[2 * t + 1] = run + v0;
#pragma unroll
    for (int k = 0; k < 2; ++k) {
        int b  = 2 * t + k;
        int vvk = (k == 0) ? v0 : v1;
        if (b < nb && vvk > 0) {
            int old = atomicAdd(&bucket_cursor[b], vvk);   // delta in bucket
            ldelta[b] = b * BCAP + old - loff[b];
        }
    }
    __syncthreads();
#pragma unroll
    for (int k = 0; k < 2; ++k) {
        int i4 = t + k * P1_DIM;
        if (i4 < full4) {
            int u4[4] = {uu[k].x, uu[k].y, uu[k].z, uu[k].w};
            int v4[4] = {vv[k].x, vv[k].y, vv[k].z, vv[k].w};
#pragma unroll
            for (int e = 0; e < 4; ++e) {
                int ub = u4[e] >> NB_SHIFT;
                int s1 = loff[ub] + rka[4 * k + e];
                stage[s1]  = ((u4[e] & 255) << 18) | v4[e];
                bstage[s1] = (unsigned short)ub;
                int vb = v4[e] >> NB_SHIFT;
                int s2 = loff[vb] + rkb[4 * k + e];
                stage[s2]  = ((v4[e] & 255) << 18) | u4[e];
                bstage[s2] = (unsigned short)vb;
            }
        }
    }
    if (has_rem) {
        int ub = ur >> NB_SHIFT;
        int s1 = loff[ub] + rkra;
        stage[s1]  = ((ur & 255) << 18) | vr;
        bstage[s1] = (unsigned short)ub;
        int vb = vr >> NB_SHIFT;
        int s2 = loff[vb] + rkrb;
        stage[s2]  = ((vr & 255) << 18) | ur;
        bstage[s2] = (unsigned short)vb;
    }
    __syncthreads();
    int total = 2 * cnt_here;
    for (int s = t; s < total; s += P1_DIM) {
        tmp[s + ldelta[bstage[s]]] = stage[s];
    }
}

// ---- per-bucket finalize: self-prefix, row_ptr, dis/dis2/invd, cv, Y0 ----
__global__ __launch_bounds__(256) void finalize_kernel(
    const int* __restrict__ tmp, const int* __restrict__ bcur,
    const float4* __restrict__ ut4, const float4* __restrict__ it4,
    int* __restrict__ row_ptr, float* __restrict__ dis,
    float* __restrict__ dis2, float* __restrict__ invd,
    int* __restrict__ cv, half8* __restrict__ Yh0,
    int usernum, int n_nodes, int nb, int nnz) {
    __shared__ int   rcnt[256];
    __shared__ int   ccur[256];
    __shared__ int   wsum[4];
    __shared__ int   red[256];
    __shared__ float sdis[256];
    int b = blockIdx.x;
    int t = threadIdx.x;
    int lane = t & 63, wv = t >> 6;
    // self-computed exclusive prefix of bcur over buckets < b
    int partial = 0;
    for (int i = t; i < nb; i += 256) {
        int c = bcur[i];
        if (i < b) partial += c;
    }
    red[t] = partial;
    __syncthreads();
    for (int off = 128; off > 0; off >>= 1) {
        if (t < off) red[t] += red[t + off];
        __syncthreads();
    }
    int dbeg  = red[0];
    int count = bcur[b];
    int src   = b * BCAP;
    rcnt[t] = 0;
    __syncthreads();
    for (int i = t; i < count; i += 256) {
        atomicAdd(&rcnt[tmp[src + i] >> 18], 1);
    }
    __syncthreads();
    int v = rcnt[t];
    int sc = v;
#pragma unroll
    for (int off = 1; off < 64; off <<= 1) {
        int x = __shfl_up(sc, off);
        if (lane >= off) sc += x;
    }
    if (lane == 63) wsum[wv] = sc;
    __syncthreads();
    int prefix = 0;
#pragma unroll
    for (int k = 0; k < 4; ++k) {
        int s = wsum[k];
        prefix += (k < wv) ? s : 0;
    }
    int ex = prefix + sc - v;
    ccur[t] = ex;
    int row = (b << NB_SHIFT) + t;
    float dval = 0.0f;
    if (row < n_nodes) {
        row_ptr[row] = dbeg + ex;
        double dv = (double)v;
        dval      = (v > 0) ? (float)(1.0 / sqrt(dv)) : 0.0f;
        dis[row]  = dval;
        dis2[row] = (v > 0) ? (float)(1.0 / dv) : 0.0f;
        invd[row] = (v > 0) ? (float)sqrt(dv) : 0.0f;
    }
    sdis[t] = dval;
    if (b == nb - 1 && t == 0) row_ptr[n_nodes] = nnz;
    __syncthreads();
    // rank + direct cv write: dest window ~28KB -> L2 write-merge
    for (int i = t; i < count; i += 256) {
        int p  = tmp[src + i];
        int rk = atomicAdd(&ccur[p >> 18], 1);
        cv[dbeg + rk] = p & 0x3FFFF;
    }
    // fused convert: Y0[row] = dis[row] * X0[row] (fp16, 128B rows)
    int row0 = b << NB_SHIFT;
    for (int i = t; i < 256 * 8; i += 256) {
        int rl = i >> 3;
        int rg = row0 + rl;
        if (rg < n_nodes) {
            int c = i & 7;
            float d = sdis[rl];
            const float4* srcp = (rg <= usernum)
                ? (ut4 + (size_t)rg * 16 + 2 * c)
                : (it4 + (size_t)(rg - usernum) * 16 + 2 * c);
            float4 a = srcp[0];
            float4 e = srcp[1];
            half8 o;
            o[0] = (_Float16)(d * a.x); o[1] = (_Float16)(d * a.y);
            o[2] = (_Float16)(d * a.z); o[3] = (_Float16)(d * a.w);
            o[4] = (_Float16)(d * e.x); o[5] = (_Float16)(d * e.y);
            o[6] = (_Float16)(d * e.z); o[7] = (_Float16)(d * e.w);
            Yh0[(size_t)rg * 8 + c] = o;
        }
    }
}

// ---- pure gather-sum CSR row: 8 edge-slots x 8 lanes x half8 ----
// Halving-butterfly reduction: returns ONE element per lane, for
// dim d = l8*8 + k with k = (g&1)*4 + (g&2) + (g>>2).
__device__ inline float csr_row_sum_h(const _Float16* __restrict__ Yh,
                                      const int* __restrict__ cv,
                                      int beg, int end, int g, int l8,
                                      float one) {
    float acc[8] = {0.f, 0.f, 0.f, 0.f, 0.f, 0.f, 0.f, 0.f};
    const char* Yb = (const char*)Yh;
    const char* cb = (const char*)cv;
    unsigned lo = (unsigned)l8 * 16u;
    int j = beg + g;
    for (; j + 8 < end; j += 16) {
        unsigned c0 = (unsigned)*(const int*)(cb + ((unsigned)j << 2));
        unsigned c1 = (unsigned)*(const int*)(cb + ((unsigned)(j + 8) << 2));
        half8 x0 = *(const half8*)(Yb + (c0 << 7) + lo);
        half8 x1 = *(const half8*)(Yb + (c1 << 7) + lo);
        half8 tt = x0 + x1;   // 4x v_pk_add_f16
#pragma unroll
        for (int k = 0; k < 8; ++k) {
            acc[k] += one * (float)tt[k];   // v_mad_mix_f32
        }
    }
    if (j < end) {
        unsigned c0 = (unsigned)*(const int*)(cb + ((unsigned)j << 2));
        half8 x0 = *(const half8*)(Yb + (c0 << 7) + lo);
#pragma unroll
        for (int k = 0; k < 8; ++k) {
            acc[k] += one * (float)x0[k];
        }
    }
    bool gb0 = (g & 1) != 0;
    bool gb1 = (g & 2) != 0;
    bool gb2 = (g & 4) != 0;
    float s0 = gb0 ? acc[0] : acc[4];
    float s1 = gb0 ? acc[1] : acc[5];
    float s2 = gb0 ? acc[2] : acc[6];
    float s3 = gb0 ? acc[3] : acc[7];
    float a0 = (gb0 ? acc[4] : acc[0]) + __shfl_xor(s0, 8);
    float a1 = (gb0 ? acc[5] : acc[1]) + __shfl_xor(s1, 8);
    float a2 = (gb0 ? acc[6] : acc[2]) + __shfl_xor(s2, 8);
    float a3 = (gb0 ? acc[7] : acc[3]) + __shfl_xor(s3, 8);
    float t0 = gb1 ? a0 : a2;
    float t1 = gb1 ? a1 : a3;
    float b0 = (gb1 ? a2 : a0) + __shfl_xor(t0, 16);
    float b1 = (gb1 ? a3 : a1) + __shfl_xor(t1, 16);
    float u = gb2 ? b0 : b1;
    float fin = (gb2 ? b1 : b0) + __shfl_xor(u, 32);
    return fin;
}

__device__ inline int lane_dim(int g, int l8) {
    return l8 * 8 + ((g & 1) * 4 + (g & 2) + (g >> 2));
}

// Y_{l+1}[r] = (1/deg[r]) * sum_e Y_l[c]
__global__ __launch_bounds__(256) void spmm_y_kernel(
    const _Float16* __restrict__ Yin, _Float16* __restrict__ Yout,
    const int* __restrict__ row_ptr, const int* __restrict__ cv,
    const float* __restrict__ dis2, float one, int n_nodes) {
    int wid  = (blockIdx.x * blockDim.x + threadIdx.x) >> 6;
    int lane = threadIdx.x & 63;
    if (wid >= n_nodes) return;
    int beg = row_ptr[wid];
    int end = row_ptr[wid + 1];
    float d2 = dis2[wid];
    int g = lane >> 3, l8 = lane & 7;
    float fin = csr_row_sum_h(Yin, cv, beg, end, g, l8, one);
    int d = lane_dim(g, l8);
    Yout[(size_t)wid * 64 + d] = (_Float16)(fin * d2);
}

// fused layer-3 + gather + logits: one wave per batch element.
// emb(idx)[d] = X0fp32[idx][d] + invd*(Y1+Y2)[idx][d] + dis*rowdot(Y2)[d];
// out[b] = <emb(u), emb(pos)>/16; out[B+b] = <emb(u), emb(neg)>/16.
__global__ __launch_bounds__(256) void gather_logits_kernel(
    const float* __restrict__ ut, const float* __restrict__ itb,
    const _Float16* __restrict__ Y1, const _Float16* __restrict__ Y2,
    const int* __restrict__ row_ptr, const int* __restrict__ cv,
    const float* __restrict__ dis, const float* __restrict__ invd,
    const int* __restrict__ user_ids, const int* __restrict__ pos_seqs,
    const int* __restrict__ neg_seqs, float* __restrict__ out,
    float one, int usernum, int itemnum, int batch) {
    int w    = (blockIdx.x * blockDim.x + threadIdx.x) >> 6;
    int lane = threadIdx.x & 63;
    if (w >= batch) return;
    int g = lane >> 3, l8 = lane & 7;
    int d = lane_dim(g, l8);
    int idxs[3];
    int u = min(max(user_ids[w], 0), usernum);
    idxs[0] = u;
    int p = min(max(pos_seqs[w], 1), itemnum);
    idxs[1] = usernum + p;
    int nn = min(max(neg_seqs[w], 1), itemnum);
    idxs[2] = usernum + nn;
    float vals[3];
#pragma unroll
    for (int q = 0; q < 3; ++q) {
        int idx = idxs[q];
        int beg = row_ptr[idx];
        int end = row_ptr[idx + 1];
        float dr = dis[idx];
        float iv = invd[idx];
        float fin = csr_row_sum_h(Y2, cv, beg, end, g, l8, one);
        const float* base0 = (q == 0) ? (ut + (size_t)u * 64)
                                      : (itb + (size_t)(idx - usernum) * 64);
        float x0v = base0[d];
        float y1v = (float)Y1[(size_t)idx * 64 + d];
        float y2v = (float)Y2[(size_t)idx * 64 + d];
        vals[q] = x0v + iv * (y1v + y2v) + fin * dr;
    }
    float dp = vals[0] * vals[1];
    float dn = vals[0] * vals[2];
#pragma unroll
    for (int off = 1; off < 64; off <<= 1) {
        dp += __shfl_xor(dp, off);
        dn += __shfl_xor(dn, off);
    }
    if (lane == 0) {
        out[w]         = dp * 0.0625f;
        out[batch + w] = dn * 0.0625f;
    }
}

extern "C" void kernel_launch(void* const* d_in, const int* in_sizes, int n_in,
                              void* d_out, int out_size, void* d_ws,
                              size_t ws_size, hipStream_t stream) {
    const float* user_table = (const float*)d_in[0];
    const float* item_table = (const float*)d_in[1];
    const int*   rows       = (const int*)d_in[3];
    const int*   cols       = (const int*)d_in[4];
    const int*   user_ids   = (const int*)d_in[5];
    const int*   pos_seqs   = (const int*)d_in[6];
    const int*   neg_seqs   = (const int*)d_in[7];
    float*       out        = (float*)d_out;

    const int D = 64;
    int usernum = in_sizes[0] / D - 1;   // 100000
    int itemnum = in_sizes[1] / D - 1;   // 50000
    int nnz     = in_sizes[2];           // 4,000,000
    int batch   = in_sizes[5];           // 4096
    int n_nodes = usernum + itemnum + 1; // 150001
    int nb      = (n_nodes + (1 << NB_SHIFT) - 1) >> NB_SHIFT;  // 586
    int M       = nnz >> 1;              // 2,000,000 source pairs (mirror COO)

    // ---- workspace layout ----
    char* w = (char*)d_ws;
    auto alloc = [&](size_t bytes) {
        char* p = w;
        w += (bytes + 255) & ~(size_t)255;
        return p;
    };
    _Float16* Yh0   = (_Float16*)alloc((size_t)n_nodes * D * 2);  // 19.2 MB
    _Float16* Yh1   = (_Float16*)alloc((size_t)n_nodes * D * 2);  // 19.2 MB
    _Float16* Yh2   = (_Float16*)alloc((size_t)n_nodes * D * 2);  // 19.2 MB
    int*   cv       = (int*)alloc((size_t)nnz * 4);               // 16 MB
    int*   row_ptr  = (int*)alloc((size_t)(n_nodes + 1) * 4);
    float* dis      = (float*)alloc((size_t)n_nodes * 4);
    float* dis2     = (float*)alloc((size_t)n_nodes * 4);
    float* invd     = (float*)alloc((size_t)n_nodes * 4);
    int*   bcur     = (int*)alloc(4096);
    // partition scratch: 586*16000*4 = 37.5 MB, aliases Yh1+Yh2 (38.4 MB);
    // dead after finalize; Yh1/Yh2 written only afterwards.
    int*   tmp      = (int*)Yh1;

    // ---- CSR build ----
    hipMemsetAsync(bcur, 0, 4096, stream);
    int p1_tiles = (M + P1_SRC - 1) / P1_SRC;
    partition_kernel<<<p1_tiles, P1_DIM, 0, stream>>>(rows, cols, bcur, tmp,
                                                      M, nb);
    finalize_kernel<<<nb, 256, 0, stream>>>(
        tmp, bcur, (const float4*)user_table, (const float4*)item_table,
        row_ptr, dis, dis2, invd, cv, (half8*)Yh0, usernum, n_nodes, nb, nnz);

    // ---- layers: Yh0 -> Yh1 -> Yh2 (pure gather-sum + 1/deg scale) ----
    const float one = 1.0f;
    int spmm_grid = (n_nodes + 3) / 4;
    spmm_y_kernel<<<spmm_grid, 256, 0, stream>>>(Yh0, Yh1, row_ptr, cv, dis2,
                                                 one, n_nodes);
    spmm_y_kernel<<<spmm_grid, 256, 0, stream>>>(Yh1, Yh2, row_ptr, cv, dis2,
                                                 one, n_nodes);

    // ---- fused layer-3 + gather + logits ----
    gather_logits_kernel<<<(batch + 3) / 4, 256, 0, stream>>>(
        user_table, item_table, Yh1, Yh2, row_ptr, cv, dis, invd, user_ids,
        pos_seqs, neg_seqs, out, one, usernum, itemnum, batch);
}